// Round 2
// baseline (340.584 us; speedup 1.0000x reference)
//
#include <hip/hip_runtime.h>
#include <hip/hip_bf16.h>
#include <math.h>

// TimeWindowBlock round 7.
// R6 post-mortem: top-5 dispatches are ALL 800-MiB fillBuffer (121 us each,
// per-iteration workspace re-poison); our kernels are each <121 us, so
// dur_us 323.7 = ~242 us fill + ~8 us precompute + ~74 us twb_main.
// R7: (1) drop the workspace entirely -> single fused kernel (tests whether
// the poison leaves the timed window; c/A recomputed per block from W1,
// which is L1-resident at 36 KB); (2) register-retain key: phase 1's frag
// pattern already loads every element exactly once (16 float4/thread);
// phase 2 runs from registers -> key HBM traffic 420 MB -> 210 MB;
// (3) f32->bf16 via __float2bfloat16 so compiler emits v_cvt_pk_bf16_f32.

#define BB   512
#define WW   8
#define SS   200
#define HH   64
#define FFN  36
#define SCST 72            // c LDS row stride in bf16 (144 B -> 2-way banks, free)

typedef __attribute__((ext_vector_type(8))) short short8;
typedef __attribute__((ext_vector_type(4))) float f32x4;

__device__ __forceinline__ unsigned short f2bf(float x) {
    __hip_bfloat16 h = __float2bfloat16(x);      // RNE; pairs fuse to v_cvt_pk_bf16_f32
    union { __hip_bfloat16 b; unsigned short u; } c; c.b = h;
    return c.u;
}
__device__ __forceinline__ float bf2f(unsigned short h) {
    union { unsigned u; float f; } v; v.u = ((unsigned)h) << 16;
    return v.f;
}

__global__ __launch_bounds__(256, 2)
void twb_fused(const float* __restrict__ query,
               const float* __restrict__ key,
               const float* __restrict__ W1,
               const float* __restrict__ b1,
               const float* __restrict__ prelu_a,
               const float* __restrict__ W2,
               const int*   __restrict__ mask,
               float*       __restrict__ out)
{
    __shared__ float q_s[HH];
    __shared__ unsigned short c_s[48 * SCST];    // 6.9 KB
    __shared__ float A_s[48], W2_s[48];
    __shared__ float partA[144];
    __shared__ float scores[208];
    __shared__ float wl[208];
    __shared__ float red[8];
    __shared__ float part[4][HH];

    const int tid  = threadIdx.x;
    const int bw   = blockIdx.x;
    const int b    = bw >> 3;
    const int lane = tid & 63, q = lane >> 4, n = lane & 15, wid = tid >> 6;

    const float* kg = key + (size_t)bw * (SS * HH);

    // ---- issue ALL key loads up front (read key exactly once, keep in regs) ----
    // thread (wid,q,n), tile t: row s = (wid+4t)*16+n, cols [ks*32+q*8, +8)
    float4 kv[4][2][2];
    #pragma unroll
    for (int t = 0; t < 4; ++t) {
        const int st = wid + 4 * t;
        const int s  = st * 16 + n;
        const bool valid = (st < 13) && (s < SS);
        #pragma unroll
        for (int ks = 0; ks < 2; ++ks)
            #pragma unroll
            for (int hh = 0; hh < 2; ++hh) {
                if (valid)
                    kv[t][ks][hh] = *(const float4*)(kg + (size_t)s * HH + ks * 32 + q * 8 + hh * 4);
                else
                    kv[t][ks][hh] = make_float4(0.f, 0.f, 0.f, 0.f);
            }
    }

    // ---- prologue: q, mask, W2 ----
    int mv = 1;
    if (tid < SS) mv = mask[bw * SS + tid];
    const float pa = prelu_a[0];
    if (tid < HH) q_s[tid] = query[b * HH + tid];
    if (tid < 48) W2_s[tid] = (tid < FFN) ? W2[tid] : 0.0f;
    __syncthreads();

    // ---- per-block c (bf16, frag layout) and A (from W1; L1-hot) ----
    for (int idx = tid; idx < 48 * HH; idx += 256) {
        const int o = idx >> 6, h = idx & 63;
        float c = 0.0f;
        if (o < FFN) {
            const float* w = W1 + o * 4 * HH;
            c = w[HH + h] - w[2 * HH + h] + w[3 * HH + h] * q_s[h];
        }
        c_s[o * SCST + h] = f2bf(c);
    }
    if (tid < 144) {                       // A: 36 o x 4 chunks of 16
        const int o = tid >> 2, c4 = tid & 3;
        const float* w = W1 + o * 4 * HH;
        float a = 0.0f;
        #pragma unroll
        for (int i = 0; i < 16; ++i) {
            const int h = c4 * 16 + i;
            a += (w[h] + w[2 * HH + h]) * q_s[h];
        }
        partA[tid] = a;
    }
    __syncthreads();
    if (tid < 48)
        A_s[tid] = (tid < FFN)
                 ? (b1[tid] + partA[tid*4] + partA[tid*4+1] + partA[tid*4+2] + partA[tid*4+3])
                 : 0.0f;
    __syncthreads();

    // ---- B-frags + per-lane epilogue params ----
    short8 Bf[3][2];
    float  Ao[3], w2o[3];
    #pragma unroll
    for (int ot = 0; ot < 3; ++ot) {
        #pragma unroll
        for (int ks = 0; ks < 2; ++ks)
            Bf[ot][ks] = *(const short8*)(c_s + (ot * 16 + n) * SCST + ks * 32 + q * 8);
        Ao[ot]  = A_s[ot * 16 + n];
        w2o[ot] = W2_s[ot * 16 + n];
    }

    // ---- phase 1: MFMA score GEMM from registers ----
    #pragma unroll
    for (int t = 0; t < 4; ++t) {
        const int st = wid + 4 * t;
        if (st < 13) {
            short8 Ah[2], Al[2];
            #pragma unroll
            for (int ks = 0; ks < 2; ++ks) {
                const float vv[8] = {kv[t][ks][0].x, kv[t][ks][0].y, kv[t][ks][0].z, kv[t][ks][0].w,
                                     kv[t][ks][1].x, kv[t][ks][1].y, kv[t][ks][1].z, kv[t][ks][1].w};
                #pragma unroll
                for (int j = 0; j < 8; ++j) {
                    const unsigned short hi = f2bf(vv[j]);
                    Ah[ks][j] = (short)hi;
                    Al[ks][j] = (short)f2bf(vv[j] - bf2f(hi));
                }
            }
            float contrib[4] = {0.f, 0.f, 0.f, 0.f};
            #pragma unroll
            for (int ot = 0; ot < 3; ++ot) {
                f32x4 acc = {0.f, 0.f, 0.f, 0.f};
                acc = __builtin_amdgcn_mfma_f32_16x16x32_bf16(Ah[0], Bf[ot][0], acc, 0, 0, 0);
                acc = __builtin_amdgcn_mfma_f32_16x16x32_bf16(Al[0], Bf[ot][0], acc, 0, 0, 0);
                acc = __builtin_amdgcn_mfma_f32_16x16x32_bf16(Ah[1], Bf[ot][1], acc, 0, 0, 0);
                acc = __builtin_amdgcn_mfma_f32_16x16x32_bf16(Al[1], Bf[ot][1], acc, 0, 0, 0);
                #pragma unroll
                for (int r = 0; r < 4; ++r) {
                    float hv = acc[r] + Ao[ot];
                    hv = (hv >= 0.0f) ? hv : pa * hv;
                    contrib[r] += w2o[ot] * hv;
                }
            }
            #pragma unroll
            for (int m = 1; m <= 8; m <<= 1)
                #pragma unroll
                for (int r = 0; r < 4; ++r)
                    contrib[r] += __shfl_xor(contrib[r], m, 64);
            if (n == 0) {
                #pragma unroll
                for (int r = 0; r < 4; ++r) {
                    const int s2 = st * 16 + q * 4 + r;
                    if (s2 < SS) scores[s2] = contrib[r];
                }
            }
        }
    }
    __syncthreads();

    // ---- mask + softmax over S ----
    float msc = -3.0e38f;
    if (tid < SS)
        msc = mv ? -10000.0f : scores[tid];
    float mx = msc;
    #pragma unroll
    for (int off = 32; off > 0; off >>= 1)
        mx = fmaxf(mx, __shfl_xor(mx, off, 64));
    if (lane == 0) red[wid] = mx;
    __syncthreads();
    const float M = fmaxf(fmaxf(red[0], red[1]), fmaxf(red[2], red[3]));
    float e = (tid < SS) ? __expf(msc - M) : 0.0f;
    float ssum = e;
    #pragma unroll
    for (int off = 32; off > 0; off >>= 1)
        ssum += __shfl_xor(ssum, off, 64);
    if (lane == 0) red[4 + wid] = ssum;
    __syncthreads();
    const float total = red[4] + red[5] + red[6] + red[7];
    if (tid < SS)       wl[tid] = e / total;
    else if (tid < 208) wl[tid] = 0.0f;
    __syncthreads();

    // ---- phase 2: out[h] = sum_s k[s][h]*wl[s], entirely from registers ----
    float acc2[2][8];
    #pragma unroll
    for (int ks = 0; ks < 2; ++ks)
        #pragma unroll
        for (int j = 0; j < 8; ++j) acc2[ks][j] = 0.0f;

    #pragma unroll
    for (int t = 0; t < 4; ++t) {
        const int st = wid + 4 * t;
        if (st < 13) {
            const int s = st * 16 + n;
            const float wgt = wl[s];            // wl[200..207]=0, kv zeroed there too
            #pragma unroll
            for (int ks = 0; ks < 2; ++ks) {
                acc2[ks][0] += wgt * kv[t][ks][0].x;
                acc2[ks][1] += wgt * kv[t][ks][0].y;
                acc2[ks][2] += wgt * kv[t][ks][0].z;
                acc2[ks][3] += wgt * kv[t][ks][0].w;
                acc2[ks][4] += wgt * kv[t][ks][1].x;
                acc2[ks][5] += wgt * kv[t][ks][1].y;
                acc2[ks][6] += wgt * kv[t][ks][1].z;
                acc2[ks][7] += wgt * kv[t][ks][1].w;
            }
        }
    }
    // reduce over the 16 n-lanes (rows), within each q-group
    #pragma unroll
    for (int m = 1; m <= 8; m <<= 1)
        #pragma unroll
        for (int ks = 0; ks < 2; ++ks)
            #pragma unroll
            for (int j = 0; j < 8; ++j)
                acc2[ks][j] += __shfl_xor(acc2[ks][j], m, 64);
    if (n == 0) {
        #pragma unroll
        for (int ks = 0; ks < 2; ++ks)
            #pragma unroll
            for (int j = 0; j < 8; ++j)
                part[wid][ks * 32 + q * 8 + j] = acc2[ks][j];
    }
    __syncthreads();
    if (tid < HH)
        out[(size_t)bw * HH + tid] = part[0][tid] + part[1][tid] + part[2][tid] + part[3][tid];
}

extern "C" void kernel_launch(void* const* d_in, const int* in_sizes, int n_in,
                              void* d_out, int out_size, void* d_ws, size_t ws_size,
                              hipStream_t stream) {
    const float* query   = (const float*)d_in[0];
    const float* key     = (const float*)d_in[1];
    const float* W1      = (const float*)d_in[2];
    const float* b1      = (const float*)d_in[3];
    const float* prelu_a = (const float*)d_in[4];
    const float* W2      = (const float*)d_in[5];
    // d_in[6] = b2: constant shift of unmasked scores; cancels in softmax
    // (masked entries are exp(-1e4 - M) == 0 either way). Verified passing R5/R6.
    const int*   mask    = (const int*)d_in[7];
    float* out = (float*)d_out;

    (void)d_ws; (void)ws_size;   // no workspace: avoids the 800-MiB re-poison fill
    twb_fused<<<BB * WW, 256, 0, stream>>>(query, key, W1, b1, prelu_a,
                                           W2, mask, out);
}

// Round 3
// 322.705 us; speedup vs baseline: 1.0554x; 1.0554x over previous
//
#include <hip/hip_runtime.h>
#include <hip/hip_bf16.h>
#include <math.h>

// TimeWindowBlock round 8.
// R7 post-mortem: the 800-MiB ws poison fill is UNCONDITIONAL (ran with ws
// untouched) -> ws is free to use. twb_fused was 125 us: register-retaining
// the key tile pushed ~190 total regs (68 VGPR + AGPR spill), occupancy 31%,
// and made traffic bursty (one load burst, then reg-only phases) -> 1.7 TB/s
// effective on a 210 MB stream. Fix: wave-per-slice. Each wave owns one
// (b,w) slice end-to-end: phase-1 MFMA with a 2-deep reg double-buffer,
// wave-local softmax (shfl), phase-2 re-read from global (L3-hot, read us
// after phase 1 wrote it into L3). No __syncthreads at all; 4 independent
// waves/block; ~100 VGPRs -> launch_bounds(256,4) = 16 waves/CU all issuing
// loads continuously. c/A precomputed per-b in ws (amortized over 8 w).

#define BB   512
#define WW   8
#define SS   200
#define HH   64
#define FFN  36

typedef __attribute__((ext_vector_type(8))) short short8;
typedef __attribute__((ext_vector_type(4))) float f32x4;

__device__ __forceinline__ unsigned short f2bf(float x) {
    __hip_bfloat16 h = __float2bfloat16(x);      // RNE; pairs fuse to v_cvt_pk_bf16_f32
    union { __hip_bfloat16 b; unsigned short u; } c; c.b = h;
    return c.u;
}
__device__ __forceinline__ float bf2f(unsigned short h) {
    union { unsigned u; float f; } v; v.u = ((unsigned)h) << 16;
    return v.f;
}

// ---------------- kernel A: c_hi[b][48][64] bf16, A[b][48] f32 ----------------
__global__ __launch_bounds__(256)
void precompute_c(const float* __restrict__ query,
                  const float* __restrict__ W1,
                  const float* __restrict__ b1,
                  unsigned short* __restrict__ c_hi_g,
                  float* __restrict__ A_g)
{
    __shared__ float q_s[HH];
    const int b = blockIdx.x, tid = threadIdx.x;
    if (tid < HH) q_s[tid] = query[b * HH + tid];
    __syncthreads();
    for (int idx = tid; idx < 48 * HH; idx += 256) {
        int o = idx >> 6, h = idx & 63;
        float c = 0.0f;
        if (o < FFN) {
            const float* w = W1 + o * 4 * HH;
            c = w[HH + h] - w[2 * HH + h] + w[3 * HH + h] * q_s[h];
        }
        c_hi_g[(size_t)b * 48 * HH + idx] = f2bf(c);
    }
    if (tid < 48) {
        float a = 0.0f;
        if (tid < FFN) {
            const float* w = W1 + tid * 4 * HH;
            a = b1[tid];
            #pragma unroll 8
            for (int h = 0; h < HH; ++h) a += (w[h] + w[2 * HH + h]) * q_s[h];
        }
        A_g[b * 48 + tid] = a;
    }
}

// ---------------- helpers for the wave kernel ----------------
__device__ __forceinline__ void load_tile(const float* __restrict__ kg,
                                          int st, int n, int q,
                                          float4 (&buf)[2][2])
{
    const int s = st * 16 + n;
    const float* p = kg + (size_t)s * HH + q * 8;
    if (s < SS) {
        buf[0][0] = *(const float4*)(p);
        buf[0][1] = *(const float4*)(p + 4);
        buf[1][0] = *(const float4*)(p + 32);
        buf[1][1] = *(const float4*)(p + 36);
    } else {
        const float4 z = make_float4(0.f, 0.f, 0.f, 0.f);
        buf[0][0] = z; buf[0][1] = z; buf[1][0] = z; buf[1][1] = z;
    }
}

__device__ __forceinline__ void compute_tile(const float4 (&buf)[2][2],
                                             const short8 (&Bf)[3][2],
                                             const float (&Ao)[3],
                                             const float (&w2o)[3],
                                             float pa, int st, int q, int n,
                                             float* __restrict__ scw)
{
    short8 Ah[2], Al[2];
    #pragma unroll
    for (int ks = 0; ks < 2; ++ks) {
        const float vv[8] = {buf[ks][0].x, buf[ks][0].y, buf[ks][0].z, buf[ks][0].w,
                             buf[ks][1].x, buf[ks][1].y, buf[ks][1].z, buf[ks][1].w};
        #pragma unroll
        for (int j = 0; j < 8; ++j) {
            const unsigned short hi = f2bf(vv[j]);
            Ah[ks][j] = (short)hi;
            Al[ks][j] = (short)f2bf(vv[j] - bf2f(hi));
        }
    }
    float contrib[4] = {0.f, 0.f, 0.f, 0.f};
    #pragma unroll
    for (int ot = 0; ot < 3; ++ot) {
        f32x4 acc = {0.f, 0.f, 0.f, 0.f};
        acc = __builtin_amdgcn_mfma_f32_16x16x32_bf16(Ah[0], Bf[ot][0], acc, 0, 0, 0);
        acc = __builtin_amdgcn_mfma_f32_16x16x32_bf16(Al[0], Bf[ot][0], acc, 0, 0, 0);
        acc = __builtin_amdgcn_mfma_f32_16x16x32_bf16(Ah[1], Bf[ot][1], acc, 0, 0, 0);
        acc = __builtin_amdgcn_mfma_f32_16x16x32_bf16(Al[1], Bf[ot][1], acc, 0, 0, 0);
        #pragma unroll
        for (int r = 0; r < 4; ++r) {
            float hv = acc[r] + Ao[ot];
            hv = (hv >= 0.0f) ? hv : pa * hv;
            contrib[r] += w2o[ot] * hv;
        }
    }
    #pragma unroll
    for (int m = 1; m <= 8; m <<= 1)
        #pragma unroll
        for (int r = 0; r < 4; ++r)
            contrib[r] += __shfl_xor(contrib[r], m, 64);
    if (n == 0) {
        #pragma unroll
        for (int r = 0; r < 4; ++r)
            scw[st * 16 + q * 4 + r] = contrib[r];
    }
}

// ---------------- kernel B: one wave per (b,w) slice ----------------
__global__ __launch_bounds__(256, 4)
void twb_wave(const float* __restrict__ key,
              const unsigned short* __restrict__ c_hi_g,
              const float* __restrict__ A_g,
              const float* __restrict__ prelu_a,
              const float* __restrict__ W2,
              const int*   __restrict__ mask,
              float*       __restrict__ out)
{
    __shared__ float sc_s[4][208];          // per-wave scores, then wl (wave-local)

    const int tid  = threadIdx.x;
    const int wid  = tid >> 6, lane = tid & 63;
    const int q    = lane >> 4, n = lane & 15;
    const int bw   = blockIdx.x * 4 + wid;
    const int b    = bw >> 3;
    const float* kg = key + (size_t)bw * (SS * HH);
    float* scw = sc_s[wid];

    // ---- per-lane params: B-frags from ws (L2/L3-hot), A, W2, mask ----
    const unsigned short* cb = c_hi_g + (size_t)b * 48 * HH;
    short8 Bf[3][2];
    float  Ao[3], w2o[3];
    #pragma unroll
    for (int ot = 0; ot < 3; ++ot) {
        const int o = ot * 16 + n;
        #pragma unroll
        for (int ks = 0; ks < 2; ++ks)
            Bf[ot][ks] = *(const short8*)(cb + (size_t)o * HH + ks * 32 + q * 8);
        Ao[ot]  = A_g[b * 48 + o];
        w2o[ot] = (o < FFN) ? W2[o] : 0.0f;
    }
    const float pa = prelu_a[0];
    const int mv0 = mask[bw * SS + lane];
    const int mv1 = mask[bw * SS + 64 + lane];
    const int mv2 = mask[bw * SS + 128 + lane];
    const int mv3 = (lane < 8) ? mask[bw * SS + 192 + lane] : 1;

    // ---- phase 1: 13 MFMA tiles, 2-deep register double-buffer ----
    float4 bufA[2][2], bufB[2][2];
    load_tile(kg, 0, n, q, bufA);
    for (int st2 = 0; st2 < 6; ++st2) {
        const int st = st2 * 2;
        load_tile(kg, st + 1, n, q, bufB);
        compute_tile(bufA, Bf, Ao, w2o, pa, st, q, n, scw);
        load_tile(kg, st + 2, n, q, bufA);
        compute_tile(bufB, Bf, Ao, w2o, pa, st + 1, q, n, scw);
    }
    compute_tile(bufA, Bf, Ao, w2o, pa, 12, q, n, scw);

    // ---- wave-local mask + softmax over S (no block barrier) ----
    float sv0 = mv0 ? -10000.0f : scw[lane];
    float sv1 = mv1 ? -10000.0f : scw[64 + lane];
    float sv2 = mv2 ? -10000.0f : scw[128 + lane];
    float sv3 = (lane < 8) ? (mv3 ? -10000.0f : scw[192 + lane]) : -3.0e38f;
    float mx = fmaxf(fmaxf(sv0, sv1), fmaxf(sv2, sv3));
    #pragma unroll
    for (int off = 32; off > 0; off >>= 1)
        mx = fmaxf(mx, __shfl_xor(mx, off, 64));
    const float e0 = __expf(sv0 - mx);
    const float e1 = __expf(sv1 - mx);
    const float e2 = __expf(sv2 - mx);
    const float e3 = (lane < 8) ? __expf(sv3 - mx) : 0.0f;
    float ssum = e0 + e1 + e2 + e3;
    #pragma unroll
    for (int off = 32; off > 0; off >>= 1)
        ssum += __shfl_xor(ssum, off, 64);
    const float inv = 1.0f / ssum;
    scw[lane]       = e0 * inv;
    scw[64 + lane]  = e1 * inv;
    scw[128 + lane] = e2 * inv;
    if (lane < 8) scw[192 + lane] = e3 * inv;

    // ---- phase 2: out[h] = sum_s k[s][h]*wl[s]; k from global (L3-hot) ----
    const int h4 = n * 4;
    float4 acc2 = make_float4(0.f, 0.f, 0.f, 0.f);
    #pragma unroll 5
    for (int s = q; s < SS; s += 4) {
        const float w = scw[s];
        const float4 kv = *(const float4*)(kg + (size_t)s * HH + h4);
        acc2.x += w * kv.x; acc2.y += w * kv.y;
        acc2.z += w * kv.z; acc2.w += w * kv.w;
    }
    #pragma unroll
    for (int off = 16; off <= 32; off <<= 1) {
        acc2.x += __shfl_xor(acc2.x, off, 64);
        acc2.y += __shfl_xor(acc2.y, off, 64);
        acc2.z += __shfl_xor(acc2.z, off, 64);
        acc2.w += __shfl_xor(acc2.w, off, 64);
    }
    if (lane < 16)
        *(float4*)(out + (size_t)bw * HH + h4) = acc2;
}

// ---------------- fallback (used only if ws too small) ----------------
#define PADQ 17
__global__ __launch_bounds__(256, 2)
void twb_fallback(const float* __restrict__ query,
                  const float* __restrict__ key,
                  const float* __restrict__ W1,
                  const float* __restrict__ b1,
                  const float* __restrict__ prelu_a,
                  const float* __restrict__ W2,
                  const float* __restrict__ b2,
                  const int*   __restrict__ mask,
                  float*       __restrict__ out)
{
    __shared__ float q_s[HH];
    __shared__ float c_s[FFN * HH];
    __shared__ float A_s[FFN];
    __shared__ float W2_s[FFN];
    __shared__ float k_s[SS * PADQ * 4];
    __shared__ float wl[256];
    __shared__ float red[8];
    __shared__ float part[4 * 64];

    const int tid = threadIdx.x;
    const int bw  = blockIdx.x;
    const int b   = bw >> 3;

    if (tid < HH)  q_s[tid]  = query[b * HH + tid];
    if (tid < FFN) W2_s[tid] = W2[tid];
    __syncthreads();

    const float4* gk4 = (const float4*)(key + (size_t)bw * (SS * HH));
    float4* kl4 = (float4*)k_s;
    for (int i = tid; i < (SS * HH) / 4; i += 256) {
        float4 v = gk4[i];
        kl4[(i >> 4) * PADQ + (i & 15)] = v;
    }
    for (int idx = tid; idx < FFN * HH; idx += 256) {
        int o = idx >> 6, h = idx & 63;
        const float* w = W1 + o * (4 * HH);
        c_s[idx] = w[HH + h] - w[2 * HH + h] + w[3 * HH + h] * q_s[h];
    }
    if (tid < FFN) {
        const float* w = W1 + tid * (4 * HH);
        float a = b1[tid];
        for (int h = 0; h < HH; ++h) a += (w[h] + w[2 * HH + h]) * q_s[h];
        A_s[tid] = a;
    }
    __syncthreads();

    const float pa  = prelu_a[0];
    const float bb2 = b2[0];
    float msc = -3.0e38f;
    if (tid < SS) {
        float acc[FFN];
        #pragma unroll
        for (int o = 0; o < FFN; ++o) acc[o] = A_s[o];
        const float4* c4 = (const float4*)c_s;
        const float4* k4 = (const float4*)k_s;
        const int rowbase = tid * PADQ;
        for (int ch = 0; ch < 4; ++ch) {
            float4 kv0 = k4[rowbase + ch * 4 + 0];
            float4 kv1 = k4[rowbase + ch * 4 + 1];
            float4 kv2 = k4[rowbase + ch * 4 + 2];
            float4 kv3 = k4[rowbase + ch * 4 + 3];
            #pragma unroll
            for (int o = 0; o < FFN; ++o) {
                float4 c0 = c4[o * 16 + ch * 4 + 0];
                float4 c1 = c4[o * 16 + ch * 4 + 1];
                float4 c2 = c4[o * 16 + ch * 4 + 2];
                float4 c3 = c4[o * 16 + ch * 4 + 3];
                float a = acc[o];
                a += c0.x * kv0.x + c0.y * kv0.y + c0.z * kv0.z + c0.w * kv0.w;
                a += c1.x * kv1.x + c1.y * kv1.y + c1.z * kv1.z + c1.w * kv1.w;
                a += c2.x * kv2.x + c2.y * kv2.y + c2.z * kv2.z + c2.w * kv2.w;
                a += c3.x * kv3.x + c3.y * kv3.y + c3.z * kv3.z + c3.w * kv3.w;
                acc[o] = a;
            }
        }
        float sc = bb2;
        #pragma unroll
        for (int o = 0; o < FFN; ++o) {
            float a = acc[o];
            a = (a >= 0.0f) ? a : pa * a;
            sc += W2_s[o] * a;
        }
        msc = mask[bw * SS + tid] ? -10000.0f : sc;
    }

    float mx = msc;
    #pragma unroll
    for (int off = 32; off > 0; off >>= 1)
        mx = fmaxf(mx, __shfl_xor(mx, off, 64));
    const int wid = tid >> 6;
    if ((tid & 63) == 0) red[wid] = mx;
    __syncthreads();
    const float M = fmaxf(fmaxf(red[0], red[1]), fmaxf(red[2], red[3]));
    float e = (tid < SS) ? __expf(msc - M) : 0.0f;
    float ssum = e;
    #pragma unroll
    for (int off = 32; off > 0; off >>= 1)
        ssum += __shfl_xor(ssum, off, 64);
    if ((tid & 63) == 0) red[4 + wid] = ssum;
    __syncthreads();
    const float total = red[4] + red[5] + red[6] + red[7];
    if (tid < SS) wl[tid] = e / total;
    __syncthreads();

    const int wv = tid >> 6, h = tid & 63;
    float p = 0.0f;
    for (int s = wv * 50; s < wv * 50 + 50; ++s)
        p += k_s[s * (PADQ * 4) + h] * wl[s];
    part[wv * 64 + h] = p;
    __syncthreads();
    if (tid < 64) {
        float r = part[tid] + part[64 + tid] + part[128 + tid] + part[192 + tid];
        out[(size_t)bw * HH + tid] = r;
    }
}

extern "C" void kernel_launch(void* const* d_in, const int* in_sizes, int n_in,
                              void* d_out, int out_size, void* d_ws, size_t ws_size,
                              hipStream_t stream) {
    const float* query   = (const float*)d_in[0];
    const float* key     = (const float*)d_in[1];
    const float* W1      = (const float*)d_in[2];
    const float* b1      = (const float*)d_in[3];
    const float* prelu_a = (const float*)d_in[4];
    const float* W2      = (const float*)d_in[5];
    const float* b2      = (const float*)d_in[6];   // cancels in softmax
    const int*   mask    = (const int*)d_in[7];
    float* out = (float*)d_out;

    const size_t c_bytes = (size_t)BB * 48 * HH * sizeof(unsigned short); // 3.15 MB
    const size_t a_bytes = (size_t)BB * 48 * sizeof(float);               // 98 KB
    if (ws_size >= c_bytes + a_bytes) {
        unsigned short* c_hi_g = (unsigned short*)d_ws;
        float* A_g = (float*)((char*)d_ws + c_bytes);
        precompute_c<<<BB, 256, 0, stream>>>(query, W1, b1, c_hi_g, A_g);
        twb_wave<<<(BB * WW) / 4, 256, 0, stream>>>(key, c_hi_g, A_g, prelu_a,
                                                    W2, mask, out);
    } else {
        twb_fallback<<<BB * WW, 256, 0, stream>>>(query, key, W1, b1, prelu_a,
                                                  W2, b2, mask, out);
    }
}

// Round 4
// 316.111 us; speedup vs baseline: 1.0774x; 1.0209x over previous
//
#include <hip/hip_runtime.h>
#include <hip/hip_bf16.h>
#include <math.h>

// TimeWindowBlock round 9.
// R8 post-mortem: twb_wave ~100 us (not in top-5; dur 322.7 = fill 124 +
// ~90 fixed harness overhead + precompute 8 + kernel). Phase-2 "L3-hot"
// re-read was wrong at scale: all 4096 waves are co-resident, so the reuse
// distance between a wave's phase-1 read and its phase-2 re-read is the
// whole 210 MB tensor -> phase 2 misses L3 -> ~420 MB key traffic -> ~66 us
// floor + overlap losses. R9: online (flash-style) softmax. Per 16-row
// tile: MFMA scores -> register transpose (3 cndmask + 1 bpermute, no LDS)
// -> running (m,l) rescale -> o = o*scale + w*k from the SAME registers the
// MFMA consumed. Key read exactly once (210 MB); zero LDS in main kernel;
// mask pre-packed into a 13-bit register per lane.

#define BB   512
#define WW   8
#define SS   200
#define HH   64
#define FFN  36

typedef __attribute__((ext_vector_type(8))) short short8;
typedef __attribute__((ext_vector_type(4))) float f32x4;

__device__ __forceinline__ unsigned short f2bf(float x) {
    __hip_bfloat16 h = __float2bfloat16(x);      // RNE; pairs fuse to v_cvt_pk_bf16_f32
    union { __hip_bfloat16 b; unsigned short u; } c; c.b = h;
    return c.u;
}
__device__ __forceinline__ float bf2f(unsigned short h) {
    union { unsigned u; float f; } v; v.u = ((unsigned)h) << 16;
    return v.f;
}

// ---------------- kernel A: c_hi[b][48][64] bf16, A[b][48] f32 ----------------
__global__ __launch_bounds__(256)
void precompute_c(const float* __restrict__ query,
                  const float* __restrict__ W1,
                  const float* __restrict__ b1,
                  unsigned short* __restrict__ c_hi_g,
                  float* __restrict__ A_g)
{
    __shared__ float q_s[HH];
    const int b = blockIdx.x, tid = threadIdx.x;
    if (tid < HH) q_s[tid] = query[b * HH + tid];
    __syncthreads();
    for (int idx = tid; idx < 48 * HH; idx += 256) {
        int o = idx >> 6, h = idx & 63;
        float c = 0.0f;
        if (o < FFN) {
            const float* w = W1 + o * 4 * HH;
            c = w[HH + h] - w[2 * HH + h] + w[3 * HH + h] * q_s[h];
        }
        c_hi_g[(size_t)b * 48 * HH + idx] = f2bf(c);
    }
    if (tid < 48) {
        float a = 0.0f;
        if (tid < FFN) {
            const float* w = W1 + tid * 4 * HH;
            a = b1[tid];
            #pragma unroll 8
            for (int h = 0; h < HH; ++h) a += (w[h] + w[2 * HH + h]) * q_s[h];
        }
        A_g[b * 48 + tid] = a;
    }
}

// ---------------- helpers ----------------
__device__ __forceinline__ void load_tile(const float* __restrict__ kg,
                                          int st, int n, int q,
                                          float4 (&buf)[2][2])
{
    const int s = st * 16 + n;
    const float* p = kg + (size_t)s * HH + q * 8;
    if (s < SS) {
        buf[0][0] = *(const float4*)(p);
        buf[0][1] = *(const float4*)(p + 4);
        buf[1][0] = *(const float4*)(p + 32);
        buf[1][1] = *(const float4*)(p + 36);
    } else {
        const float4 z = make_float4(0.f, 0.f, 0.f, 0.f);
        buf[0][0] = z; buf[0][1] = z; buf[1][0] = z; buf[1][1] = z;
    }
}

__device__ __forceinline__ void online_tile(const float4 (&buf)[2][2],
                                            const short8 (&Bf)[3][2],
                                            const float (&Ao)[3],
                                            const float (&w2o)[3],
                                            float pa, int st, int q, int n,
                                            unsigned mbits,
                                            float& m, float& l, float (&o)[16])
{
    // ---- scores for this 16-row tile ----
    short8 Ah[2], Al[2];
    #pragma unroll
    for (int ks = 0; ks < 2; ++ks) {
        const float vv[8] = {buf[ks][0].x, buf[ks][0].y, buf[ks][0].z, buf[ks][0].w,
                             buf[ks][1].x, buf[ks][1].y, buf[ks][1].z, buf[ks][1].w};
        #pragma unroll
        for (int j = 0; j < 8; ++j) {
            const unsigned short hi = f2bf(vv[j]);
            Ah[ks][j] = (short)hi;
            Al[ks][j] = (short)f2bf(vv[j] - bf2f(hi));
        }
    }
    float contrib[4] = {0.f, 0.f, 0.f, 0.f};
    #pragma unroll
    for (int ot = 0; ot < 3; ++ot) {
        f32x4 acc = {0.f, 0.f, 0.f, 0.f};
        acc = __builtin_amdgcn_mfma_f32_16x16x32_bf16(Ah[0], Bf[ot][0], acc, 0, 0, 0);
        acc = __builtin_amdgcn_mfma_f32_16x16x32_bf16(Al[0], Bf[ot][0], acc, 0, 0, 0);
        acc = __builtin_amdgcn_mfma_f32_16x16x32_bf16(Ah[1], Bf[ot][1], acc, 0, 0, 0);
        acc = __builtin_amdgcn_mfma_f32_16x16x32_bf16(Al[1], Bf[ot][1], acc, 0, 0, 0);
        #pragma unroll
        for (int r = 0; r < 4; ++r) {
            float hv = acc[r] + Ao[ot];
            hv = (hv >= 0.0f) ? hv : pa * hv;
            contrib[r] += w2o[ot] * hv;
        }
    }
    #pragma unroll
    for (int mm = 1; mm <= 8; mm <<= 1)
        #pragma unroll
        for (int r = 0; r < 4; ++r)
            contrib[r] += __shfl_xor(contrib[r], mm, 64);
    // contrib[r] @ lane(q,n) = score(row q*4+r), replicated over n.

    // ---- transpose: lane(q,n) <- score(row n) ----
    const int rsel = n & 3;
    float v = contrib[0];
    v = (rsel == 1) ? contrib[1] : v;
    v = (rsel == 2) ? contrib[2] : v;
    v = (rsel == 3) ? contrib[3] : v;
    // source lane (q_s = n>>2, n_s = n&3): its v = score(row (n>>2)*4 + (n&3)) = row n
    const float srow = __shfl(v, ((n >> 2) << 4) | (n & 3), 64);

    // ---- mask + validity ----
    const int s_row = st * 16 + n;
    float sn = (s_row < SS)
             ? (((mbits >> st) & 1u) ? -10000.0f : srow)
             : -3.0e38f;

    // ---- online (m, l, o) update ----
    float tm = sn;
    #pragma unroll
    for (int mm = 1; mm <= 8; mm <<= 1)
        tm = fmaxf(tm, __shfl_xor(tm, mm, 64));
    const float m_new = fmaxf(m, tm);
    const float scl = __expf(m - m_new);     // first tile: exp(-inf)=0
    const float w   = __expf(sn - m_new);    // invalid rows: exp(-inf)=0
    float ls = w;
    #pragma unroll
    for (int mm = 1; mm <= 8; mm <<= 1)
        ls += __shfl_xor(ls, mm, 64);
    l = l * scl + ls;
    m = m_new;
    #pragma unroll
    for (int ks = 0; ks < 2; ++ks) {
        o[ks*8+0] = o[ks*8+0]*scl + w*buf[ks][0].x;
        o[ks*8+1] = o[ks*8+1]*scl + w*buf[ks][0].y;
        o[ks*8+2] = o[ks*8+2]*scl + w*buf[ks][0].z;
        o[ks*8+3] = o[ks*8+3]*scl + w*buf[ks][0].w;
        o[ks*8+4] = o[ks*8+4]*scl + w*buf[ks][1].x;
        o[ks*8+5] = o[ks*8+5]*scl + w*buf[ks][1].y;
        o[ks*8+6] = o[ks*8+6]*scl + w*buf[ks][1].z;
        o[ks*8+7] = o[ks*8+7]*scl + w*buf[ks][1].w;
    }
}

// ---------------- kernel B: one wave per (b,w) slice, single pass ----------------
__global__ __launch_bounds__(256, 4)
void twb_flash(const float* __restrict__ key,
               const unsigned short* __restrict__ c_hi_g,
               const float* __restrict__ A_g,
               const float* __restrict__ prelu_a,
               const float* __restrict__ W2,
               const int*   __restrict__ mask,
               float*       __restrict__ out)
{
    const int tid  = threadIdx.x;
    const int wid  = tid >> 6, lane = tid & 63;
    const int q    = lane >> 4, n = lane & 15;
    const int bw   = blockIdx.x * 4 + wid;
    const int b    = bw >> 3;
    const float* kg = key + (size_t)bw * (SS * HH);

    // ---- per-lane params: B-frags (L2-hot ws), A, W2 ----
    const unsigned short* cb = c_hi_g + (size_t)b * 48 * HH;
    short8 Bf[3][2];
    float  Ao[3], w2o[3];
    #pragma unroll
    for (int ot = 0; ot < 3; ++ot) {
        const int o = ot * 16 + n;
        #pragma unroll
        for (int ks = 0; ks < 2; ++ks)
            Bf[ot][ks] = *(const short8*)(cb + (size_t)o * HH + ks * 32 + q * 8);
        Ao[ot]  = A_g[b * 48 + o];
        w2o[ot] = (o < FFN) ? W2[o] : 0.0f;
    }
    const float pa = prelu_a[0];

    // ---- pack this lane's 13 mask bits (row n of each tile) ----
    unsigned mbits = 0;
    #pragma unroll
    for (int st = 0; st < 13; ++st) {
        const int s = st * 16 + n;
        int mv = 1;
        if (s < SS) mv = mask[bw * SS + s];
        mbits |= (mv ? 1u : 0u) << st;
    }

    // ---- single pass: 13 tiles, 2-deep register double-buffer ----
    float m = -3.0e38f, l = 0.0f;
    float o[16];
    #pragma unroll
    for (int j = 0; j < 16; ++j) o[j] = 0.0f;

    float4 bufA[2][2], bufB[2][2];
    load_tile(kg, 0, n, q, bufA);
    for (int st2 = 0; st2 < 6; ++st2) {
        load_tile(kg, st2 * 2 + 1, n, q, bufB);
        online_tile(bufA, Bf, Ao, w2o, pa, st2 * 2, q, n, mbits, m, l, o);
        load_tile(kg, st2 * 2 + 2, n, q, bufA);
        online_tile(bufB, Bf, Ao, w2o, pa, st2 * 2 + 1, q, n, mbits, m, l, o);
    }
    online_tile(bufA, Bf, Ao, w2o, pa, 12, q, n, mbits, m, l, o);

    // ---- reduce o over the 16 rows (n lanes), normalize, store ----
    #pragma unroll
    for (int mm = 1; mm <= 8; mm <<= 1)
        #pragma unroll
        for (int j = 0; j < 16; ++j)
            o[j] += __shfl_xor(o[j], mm, 64);
    if (n == 0) {
        const float inv = 1.0f / l;
        float* po = out + (size_t)bw * HH;
        float4 v;
        v = make_float4(o[0]*inv,  o[1]*inv,  o[2]*inv,  o[3]*inv);
        *(float4*)(po + q * 8)      = v;
        v = make_float4(o[4]*inv,  o[5]*inv,  o[6]*inv,  o[7]*inv);
        *(float4*)(po + q * 8 + 4)  = v;
        v = make_float4(o[8]*inv,  o[9]*inv,  o[10]*inv, o[11]*inv);
        *(float4*)(po + 32 + q * 8) = v;
        v = make_float4(o[12]*inv, o[13]*inv, o[14]*inv, o[15]*inv);
        *(float4*)(po + 36 + q * 8) = v;
    }
}

// ---------------- fallback (used only if ws too small) ----------------
#define PADQ 17
__global__ __launch_bounds__(256, 2)
void twb_fallback(const float* __restrict__ query,
                  const float* __restrict__ key,
                  const float* __restrict__ W1,
                  const float* __restrict__ b1,
                  const float* __restrict__ prelu_a,
                  const float* __restrict__ W2,
                  const float* __restrict__ b2,
                  const int*   __restrict__ mask,
                  float*       __restrict__ out)
{
    __shared__ float q_s[HH];
    __shared__ float c_s[FFN * HH];
    __shared__ float A_s[FFN];
    __shared__ float W2_s[FFN];
    __shared__ float k_s[SS * PADQ * 4];
    __shared__ float wl[256];
    __shared__ float red[8];
    __shared__ float part[4 * 64];

    const int tid = threadIdx.x;
    const int bw  = blockIdx.x;
    const int b   = bw >> 3;

    if (tid < HH)  q_s[tid]  = query[b * HH + tid];
    if (tid < FFN) W2_s[tid] = W2[tid];
    __syncthreads();

    const float4* gk4 = (const float4*)(key + (size_t)bw * (SS * HH));
    float4* kl4 = (float4*)k_s;
    for (int i = tid; i < (SS * HH) / 4; i += 256) {
        float4 v = gk4[i];
        kl4[(i >> 4) * PADQ + (i & 15)] = v;
    }
    for (int idx = tid; idx < FFN * HH; idx += 256) {
        int o = idx >> 6, h = idx & 63;
        const float* w = W1 + o * (4 * HH);
        c_s[idx] = w[HH + h] - w[2 * HH + h] + w[3 * HH + h] * q_s[h];
    }
    if (tid < FFN) {
        const float* w = W1 + tid * (4 * HH);
        float a = b1[tid];
        for (int h = 0; h < HH; ++h) a += (w[h] + w[2 * HH + h]) * q_s[h];
        A_s[tid] = a;
    }
    __syncthreads();

    const float pa  = prelu_a[0];
    const float bb2 = b2[0];
    float msc = -3.0e38f;
    if (tid < SS) {
        float acc[FFN];
        #pragma unroll
        for (int o = 0; o < FFN; ++o) acc[o] = A_s[o];
        const float4* c4 = (const float4*)c_s;
        const float4* k4 = (const float4*)k_s;
        const int rowbase = tid * PADQ;
        for (int ch = 0; ch < 4; ++ch) {
            float4 kv0 = k4[rowbase + ch * 4 + 0];
            float4 kv1 = k4[rowbase + ch * 4 + 1];
            float4 kv2 = k4[rowbase + ch * 4 + 2];
            float4 kv3 = k4[rowbase + ch * 4 + 3];
            #pragma unroll
            for (int o = 0; o < FFN; ++o) {
                float4 c0 = c4[o * 16 + ch * 4 + 0];
                float4 c1 = c4[o * 16 + ch * 4 + 1];
                float4 c2 = c4[o * 16 + ch * 4 + 2];
                float4 c3 = c4[o * 16 + ch * 4 + 3];
                float a = acc[o];
                a += c0.x * kv0.x + c0.y * kv0.y + c0.z * kv0.z + c0.w * kv0.w;
                a += c1.x * kv1.x + c1.y * kv1.y + c1.z * kv1.z + c1.w * kv1.w;
                a += c2.x * kv2.x + c2.y * kv2.y + c2.z * kv2.z + c2.w * kv2.w;
                a += c3.x * kv3.x + c3.y * kv3.y + c3.z * kv3.z + c3.w * kv3.w;
                acc[o] = a;
            }
        }
        float sc = bb2;
        #pragma unroll
        for (int o = 0; o < FFN; ++o) {
            float a = acc[o];
            a = (a >= 0.0f) ? a : pa * a;
            sc += W2_s[o] * a;
        }
        msc = mask[bw * SS + tid] ? -10000.0f : sc;
    }

    float mx = msc;
    #pragma unroll
    for (int off = 32; off > 0; off >>= 1)
        mx = fmaxf(mx, __shfl_xor(mx, off, 64));
    const int wid = tid >> 6;
    if ((tid & 63) == 0) red[wid] = mx;
    __syncthreads();
    const float M = fmaxf(fmaxf(red[0], red[1]), fmaxf(red[2], red[3]));
    float e = (tid < SS) ? __expf(msc - M) : 0.0f;
    float ssum = e;
    #pragma unroll
    for (int off = 32; off > 0; off >>= 1)
        ssum += __shfl_xor(ssum, off, 64);
    if ((tid & 63) == 0) red[4 + wid] = ssum;
    __syncthreads();
    const float total = red[4] + red[5] + red[6] + red[7];
    if (tid < SS) wl[tid] = e / total;
    __syncthreads();

    const int wv = tid >> 6, h = tid & 63;
    float p = 0.0f;
    for (int s = wv * 50; s < wv * 50 + 50; ++s)
        p += k_s[s * (PADQ * 4) + h] * wl[s];
    part[wv * 64 + h] = p;
    __syncthreads();
    if (tid < 64) {
        float r = part[tid] + part[64 + tid] + part[128 + tid] + part[192 + tid];
        out[(size_t)bw * HH + tid] = r;
    }
}

extern "C" void kernel_launch(void* const* d_in, const int* in_sizes, int n_in,
                              void* d_out, int out_size, void* d_ws, size_t ws_size,
                              hipStream_t stream) {
    const float* query   = (const float*)d_in[0];
    const float* key     = (const float*)d_in[1];
    const float* W1      = (const float*)d_in[2];
    const float* b1      = (const float*)d_in[3];
    const float* prelu_a = (const float*)d_in[4];
    const float* W2      = (const float*)d_in[5];
    const float* b2      = (const float*)d_in[6];   // cancels in softmax
    const int*   mask    = (const int*)d_in[7];
    float* out = (float*)d_out;

    const size_t c_bytes = (size_t)BB * 48 * HH * sizeof(unsigned short); // 3.15 MB
    const size_t a_bytes = (size_t)BB * 48 * sizeof(float);               // 98 KB
    if (ws_size >= c_bytes + a_bytes) {
        unsigned short* c_hi_g = (unsigned short*)d_ws;
        float* A_g = (float*)((char*)d_ws + c_bytes);
        precompute_c<<<BB, 256, 0, stream>>>(query, W1, b1, c_hi_g, A_g);
        twb_flash<<<(BB * WW) / 4, 256, 0, stream>>>(key, c_hi_g, A_g, prelu_a,
                                                     W2, mask, out);
    } else {
        twb_fallback<<<BB * WW, 256, 0, stream>>>(query, key, W1, b1, prelu_a,
                                                  W2, b2, mask, out);
    }
}